// Round 8
// baseline (360.760 us; speedup 1.0000x reference)
//
#include <hip/hip_runtime.h>

typedef __attribute__((ext_vector_type(8))) short short8;
typedef __attribute__((ext_vector_type(16))) float floatx16;
typedef unsigned int u32;
typedef unsigned short u16;
typedef unsigned long long u64;

#define NROWS 65536
#define NEMB 8192
#define DIM 64
#define LOSS_OFF ((size_t)NROWS * DIM)   // 4194304
#define IDX_OFF (LOSS_OFF + 1)
#define CAPQ 16                           // slots per (row, sublist)
#define CSTRIDE 66                        // u16 slots per row (64 + 2 pad)
#define NPRE 4                            // prepass tiles (seed runm)

// ws layout (bytes)
#define WS_EFRAG_OFF 0u                   // 1 MB   bf16 fragment-major embedding
#define WS_LPART_OFF (1u << 20)           // 2 KB   per-block loss partials (512)
#define WS_QUEUE_OFF ((1u << 20) + 8192u) // 256 KB overflow queue (65536 slots)
#define WS_QCNT_OFF  ((1u << 20) + 8192u + (256u << 10))
#define WS_LOVR_OFF  (WS_QCNT_OFF + 4u)
#define WS_NEED      (WS_QCNT_OFF + 64u)

typedef const __attribute__((address_space(1))) unsigned int GU32;
typedef __attribute__((address_space(3))) unsigned int LU32;

__device__ __forceinline__ unsigned short f2bf(float f) {  // RNE float->bf16
    u32 x = __float_as_uint(f);
    return (unsigned short)((x + 0x7fffu + ((x >> 16) & 1u)) >> 16);
}

// numpy pairwise-sum replication for sum(z^2) over 64 elements (validated R1)
__device__ __forceinline__ float zsum_np(const float* zf) {
    float r[8];
#pragma unroll
    for (int j = 0; j < 8; ++j) r[j] = zf[j] * zf[j];
#pragma unroll
    for (int i = 8; i < 64; i += 8) {
#pragma unroll
        for (int j = 0; j < 8; ++j) r[j] += zf[i + j] * zf[i + j];
    }
    return ((r[0] + r[1]) + (r[2] + r[3])) + ((r[4] + r[5]) + (r[6] + r[7]));
}

// exact fp32 dot, sequential k-ascending FMA chain (validated R1)
__device__ __forceinline__ float dot_chain(const float* zf, const float* e) {
    float acc = 0.f;
#pragma unroll
    for (int i = 0; i < 16; ++i) {
        float4 ev = ((const float4*)e)[i];
        acc = fmaf(zf[4 * i + 0], ev.x, acc);
        acc = fmaf(zf[4 * i + 1], ev.y, acc);
        acc = fmaf(zf[4 * i + 2], ev.z, acc);
        acc = fmaf(zf[4 * i + 3], ev.w, acc);
    }
    return acc;
}

// max of 16 via v_max3_f32-friendly triples
__device__ __forceinline__ float vmax16_3(const floatx16& a) {
    float m0 = fmaxf(fmaxf(a[0], a[1]), a[2]);
    float m1 = fmaxf(fmaxf(a[3], a[4]), a[5]);
    float m2 = fmaxf(fmaxf(a[6], a[7]), a[8]);
    float m3 = fmaxf(fmaxf(a[9], a[10]), a[11]);
    float m4 = fmaxf(fmaxf(a[12], a[13]), a[14]);
    float n0 = fmaxf(fmaxf(m0, m1), m2);
    float n1 = fmaxf(fmaxf(m3, m4), a[15]);
    return fmaxf(n0, n1);
}

// ---------- pass 0: convert embeddings to fragment-major bf16 ----------
extern "C" __global__ __launch_bounds__(256)
void vq_prep(const float* __restrict__ emb, u32* __restrict__ efrag,
             u32* __restrict__ qcount, float* __restrict__ loss_over) {
    int tid = blockIdx.x * 256 + threadIdx.x;     // 65536 threads
    int t = tid >> 8, kc = (tid >> 5) & 7, m = tid & 31;
    const float* e = emb + (((size_t)t * 32 + m) * 64 + kc * 8);
    float4 a = ((const float4*)e)[0];
    float4 b = ((const float4*)e)[1];
    u32 w0 = (u32)f2bf(a.x) | ((u32)f2bf(a.y) << 16);
    u32 w1 = (u32)f2bf(a.z) | ((u32)f2bf(a.w) << 16);
    u32 w2 = (u32)f2bf(b.x) | ((u32)f2bf(b.y) << 16);
    u32 w3 = (u32)f2bf(b.z) | ((u32)f2bf(b.w) << 16);
    ((uint4*)efrag)[tid] = make_uint4(w0, w1, w2, w3);
    if (tid == 0) { qcount[0] = 0u; *loss_over = 0.f; }
}

// ---------- fused screen + exact rescore + outputs ----------
// 512 blocks x 256 thr, 128 rows/block, 3 blocks/CU (LDS ~52 KB).
// Phase A: bf16 MFMA screen, per-et gated extraction -> LDS u16 sublists.
// Phase C: exact fp32 rescore of candidates, 2 lanes/row (validated R5
//          numerics). Phase D: z_q + loss epilogue. Overflow -> vq_over.
extern "C" __global__ __launch_bounds__(256, 3)
void vq_screen(const float* __restrict__ z, const u32* __restrict__ efrag,
               const float* __restrict__ emb, float* __restrict__ out,
               float* __restrict__ lpart, u32* __restrict__ queue,
               u32* __restrict__ qcount) {
    __shared__ u32 etile[8192];                   // 32 KB e-stage
    __shared__ u16 cand[128 * CSTRIDE];           // 16.5 KB candidate sublists
    __shared__ u32 cnt_l[512];                    // 2 KB: 128 rows x 4 subs
    __shared__ u32 win[128];
    __shared__ float lsum[4];
    const int tid = threadIdx.x;
    const int wave = tid >> 6, lane = tid & 63;
    const int rlo = lane & 31, h = lane >> 5;
    const int rowbase = blockIdx.x * 128 + (wave >> 1) * 64;
    const int sub = (wave & 1) * 2 + h;           // sublist id 0..3

    // --- z fragments (persistent, B-operand: n=lane&31, k=(lane>>5)*8+j) ---
    short8 zfr[2][4];
    float eps_[2];
#pragma unroll
    for (int rt = 0; rt < 2; ++rt) {
        const float* zp = z + (size_t)(rowbase + rt * 32 + rlo) * 64;
        float sa = 0.f;
#pragma unroll
        for (int s = 0; s < 4; ++s) {
            const float4* p = (const float4*)(zp + s * 16 + h * 8);
            float4 a = p[0], b = p[1];
            union { short8 v; unsigned short e[8]; } u;
            u.e[0] = f2bf(a.x); u.e[1] = f2bf(a.y);
            u.e[2] = f2bf(a.z); u.e[3] = f2bf(a.w);
            u.e[4] = f2bf(b.x); u.e[5] = f2bf(b.y);
            u.e[6] = f2bf(b.z); u.e[7] = f2bf(b.w);
            zfr[rt][s] = u.v;
            sa += fabsf(a.x) + fabsf(a.y) + fabsf(a.z) + fabsf(a.w)
                + fabsf(b.x) + fabsf(b.y) + fabsf(b.z) + fabsf(b.w);
        }
        sa += __shfl_xor(sa, 32);                 // combine the two k-halves
        eps_[rt] = fmaf(1.1e-6f, sa, 1e-7f);      // validated R2 margin
    }
    float runm[2] = { -3.4e38f, -3.4e38f };
    u32 pc[2] = { 0u, 0u };                       // lane-private append counts

    // ===== Phase A: ii<NPRE prepass (seed runm); then full 32-tile scan
    for (int ii = 0; ii < 32 + NPRE; ++ii) {
        const int t = (ii < NPRE) ? ii : (ii - NPRE);
        __syncthreads();
        {
            const u32* g = efrag + (size_t)t * 8192 + tid * 4;
            u32* l = etile + tid * 4;
#pragma unroll
            for (int r = 0; r < 8; ++r)
                __builtin_amdgcn_global_load_lds((GU32*)(g + r * 1024),
                                                 (LU32*)(l + r * 1024), 16, 0, 0);
        }
        __syncthreads();

        floatx16 acc[4][2];
#pragma unroll
        for (int et = 0; et < 4; ++et)
#pragma unroll
            for (int rt = 0; rt < 2; ++rt) acc[et][rt] = 0.f;

#pragma unroll
        for (int s = 0; s < 4; ++s) {
            short8 af[4];
#pragma unroll
            for (int et = 0; et < 4; ++et) {
                int off = (wave & 1) * 16384 + et * 4096 + (2 * s + h) * 512 + rlo * 16;
                af[et] = *(const short8*)((const char*)etile + off);
            }
#pragma unroll
            for (int et = 0; et < 4; ++et)
#pragma unroll
                for (int rt = 0; rt < 2; ++rt)
                    acc[et][rt] = __builtin_amdgcn_mfma_f32_32x32x16_bf16(
                        af[et], zfr[rt][s], acc[et][rt], 0, 0, 0);
        }

#pragma unroll
        for (int rt = 0; rt < 2; ++rt) {
            float vm[4];
#pragma unroll
            for (int et = 0; et < 4; ++et) vm[et] = vmax16_3(acc[et][rt]);
            float m64 = fmaxf(fmaxf(vm[0], vm[1]), fmaxf(vm[2], vm[3]));
            if (ii < NPRE) { runm[rt] = fmaxf(runm[rt], m64); continue; }
            if (m64 >= runm[rt] - eps_[rt]) {
                runm[rt] = fmaxf(runm[rt], m64);
                const float thr = runm[rt] - eps_[rt];
                const int ebase = t * 256 + (wave & 1) * 128;
                const int rowl = (wave >> 1) * 64 + rt * 32 + rlo;
                const u32 cbase = (u32)rowl * CSTRIDE + (u32)sub * CAPQ;
#pragma unroll
                for (int et = 0; et < 4; ++et) {
                    if (vm[et] >= thr) {          // per-et gate: 16-scan only
#pragma unroll
                        for (int r = 0; r < 16; ++r) {
                            float v = acc[et][rt][r];
                            if (v >= thr) {
                                int j = ebase + et * 32 + ((r & 3) + 8 * (r >> 2) + 4 * h);
                                if (pc[rt] < CAPQ) cand[cbase + pc[rt]] = (u16)j;
                                pc[rt]++;         // no atomics
                            }
                        }
                    }
                }
            }
        }
    }
    // ===== Phase B: publish counts
#pragma unroll
    for (int rt = 0; rt < 2; ++rt)
        cnt_l[(((wave >> 1) * 64 + rt * 32 + rlo) << 2) + sub] = pc[rt];
    __syncthreads();

    // ===== Phase C: exact fp32 rescore, 2 lanes per row
    {
        const int rl = lane & 31, half = lane >> 5;
        const int rowl = wave * 32 + rl;
        const int grow = blockIdx.x * 128 + rowl;
        const u32 ca = cnt_l[(rowl << 2) + 2 * half];
        const u32 cb = cnt_l[(rowl << 2) + 2 * half + 1];
        u32 ovf = (u32)((ca > CAPQ) | (cb > CAPQ));
        ovf |= (u32)__shfl_xor((int)ovf, 32);     // pair-OR (same row)

        if (!ovf) {
            float zf[64];
            const float4* zp = (const float4*)(z + (size_t)grow * 64);
#pragma unroll
            for (int i = 0; i < 16; ++i) {
                float4 a = zp[i];
                zf[4 * i + 0] = a.x; zf[4 * i + 1] = a.y;
                zf[4 * i + 2] = a.z; zf[4 * i + 3] = a.w;
            }
            const float zs = zsum_np(zf);
            u64 best = ~0ull;
            const u32 cbase = (u32)rowl * CSTRIDE + (u32)(2 * half) * CAPQ;
            for (u32 s = 0; s < ca; ++s) {
                u32 j = (u32)cand[cbase + s];
                float d = fmaf(-2.f, dot_chain(zf, emb + (size_t)j * 64), zs);
                u64 p = ((u64)__float_as_uint(d) << 32) | (u64)j;
                best = p < best ? p : best;
            }
            for (u32 s = 0; s < cb; ++s) {
                u32 j = (u32)cand[cbase + CAPQ + s];
                float d = fmaf(-2.f, dot_chain(zf, emb + (size_t)j * 64), zs);
                u64 p = ((u64)__float_as_uint(d) << 32) | (u64)j;
                best = p < best ? p : best;
            }
            u64 o = __shfl_xor(best, 32);         // pair-reduce (same row)
            best = o < best ? o : best;
            if (half == 0) {
                win[rowl] = (u32)best;
                out[IDX_OFF + grow] = (float)(u32)best;
            }
        } else if (half == 0) {
            // queue has 65536 slots = max possible overflow rows: no full case
            u32 pos = atomicAdd(qcount, 1u);
            queue[pos] = (u32)grow;
            win[rowl] = 0xFFFFFFFFu;
        }
    }
    __syncthreads();

    // ===== Phase D: z_q + loss epilogue (2 threads per row)
    float lp = 0.f;
    {
        const int r2 = tid >> 1, hf = tid & 1;
        const int grow2 = blockIdx.x * 128 + r2;
        const u32 wj = win[r2];
        if (wj != 0xFFFFFFFFu) {
            const float4* ep = (const float4*)(emb + (size_t)wj * 64) + hf * 8;
            const float4* zp4 = (const float4*)(z + (size_t)grow2 * 64) + hf * 8;
            float4* oq = (float4*)(out + (size_t)grow2 * 64) + hf * 8;
#pragma unroll
            for (int i = 0; i < 8; ++i) {
                float4 ev = ep[i];
                float4 zv = zp4[i];
                oq[i] = ev;
                float dx = ev.x - zv.x, dy = ev.y - zv.y;
                float dzv = ev.z - zv.z, dw = ev.w - zv.w;
                lp = fmaf(dx, dx, fmaf(dy, dy, fmaf(dzv, dzv, fmaf(dw, dw, lp))));
            }
        }
    }
#pragma unroll
    for (int off = 32; off; off >>= 1) lp += __shfl_down(lp, off);
    if (lane == 0) lsum[wave] = lp;
    __syncthreads();
    if (tid == 0)
        lpart[blockIdx.x] = (lsum[0] + lsum[1]) + (lsum[2] + lsum[3]);
}

// ---------- block-parallel drain of overflow rows ----------
extern "C" __global__ __launch_bounds__(256)
void vq_over(const float* __restrict__ z, const float* __restrict__ emb,
             const u32* __restrict__ queue, const u32* __restrict__ qcount,
             float* __restrict__ out, float* __restrict__ loss_over) {
    __shared__ u64 red[4];
    const int tid = threadIdx.x, wave = tid >> 6, lane = tid & 63;
    u32 n = qcount[0]; if (n > (u32)NROWS) n = (u32)NROWS;
    for (u32 qi = blockIdx.x; qi < n; qi += gridDim.x) {
        const int row = (int)queue[qi];
        const float4* zp = (const float4*)(z + (size_t)row * 64);
        float zf[64];
#pragma unroll
        for (int i = 0; i < 16; ++i) {
            float4 a = zp[i];
            zf[4 * i + 0] = a.x; zf[4 * i + 1] = a.y;
            zf[4 * i + 2] = a.z; zf[4 * i + 3] = a.w;
        }
        const float zs = zsum_np(zf);
        u64 best = ~0ull;
#pragma unroll 2
        for (int j = tid; j < NEMB; j += 256) {
            float d = fmaf(-2.f, dot_chain(zf, emb + (size_t)j * 64), zs);
            u64 p = ((u64)__float_as_uint(d) << 32) | (u64)j;
            best = p < best ? p : best;
        }
#pragma unroll
        for (int off = 32; off; off >>= 1) {
            u64 o = __shfl_xor(best, off);
            best = o < best ? o : best;
        }
        if (lane == 0) red[wave] = best;
        __syncthreads();
        if (tid == 0) {
            u64 b = red[0];
#pragma unroll
            for (int w = 1; w < 4; ++w) { u64 o = red[w]; b = o < b ? o : b; }
            red[0] = b;
            out[IDX_OFF + row] = (float)(u32)b;
        }
        __syncthreads();
        const u32 wj = (u32)red[0];
        float lp = 0.f;
        if (tid < 16) {
            float4 ev = ((const float4*)(emb + (size_t)wj * 64))[tid];
            float4 zv = zp[tid];
            ((float4*)(out + (size_t)row * 64))[tid] = ev;
            float dx = ev.x - zv.x, dy = ev.y - zv.y;
            float dzv = ev.z - zv.z, dw = ev.w - zv.w;
            lp = fmaf(dx, dx, fmaf(dy, dy, fmaf(dzv, dzv, dw * dw)));
        }
        if (wave == 0) {
#pragma unroll
            for (int off = 32; off; off >>= 1) lp += __shfl_down(lp, off);
            if (tid == 0) atomicAdd(loss_over, lp);
        }
        __syncthreads();
    }
}

extern "C" __global__ __launch_bounds__(256)
void vq_lossred(const float* __restrict__ lpart,
                const float* __restrict__ loss_over, float* __restrict__ out) {
    __shared__ float s[256];
    const int tid = threadIdx.x;
    float v = 0.f;
    for (int i = tid; i < 512; i += 256) v += lpart[i];
    s[tid] = v; __syncthreads();
    for (int off = 128; off; off >>= 1) {
        if (tid < off) s[tid] += s[tid + off];
        __syncthreads();
    }
    if (tid == 0) out[LOSS_OFF] = 1.25f * (s[0] + *loss_over) / 4194304.f;
}

// ================= legacy fp32 path (R1, proven) — ws-size fallback ==========
extern "C" __global__ __launch_bounds__(256, 2)
void vq_legacy(const float* __restrict__ z, const float* __restrict__ emb,
               float* __restrict__ out, float* __restrict__ ws) {
    __shared__ float tile[128 * 64];
    __shared__ float red_d[4][128];
    __shared__ int   red_i[4][128];
    const int tid = threadIdx.x, lane = tid & 63, wave = tid >> 6;
    const int r0 = blockIdx.x * 128 + lane;
    float z0f[64], z1f[64];
    {
        const float4* p0 = (const float4*)(z + (size_t)r0 * 64);
        const float4* p1 = (const float4*)(z + ((size_t)r0 + 64) * 64);
#pragma unroll
        for (int i = 0; i < 16; ++i) {
            float4 a = p0[i];
            z0f[4*i+0]=a.x; z0f[4*i+1]=a.y; z0f[4*i+2]=a.z; z0f[4*i+3]=a.w;
            float4 b = p1[i];
            z1f[4*i+0]=b.x; z1f[4*i+1]=b.y; z1f[4*i+2]=b.z; z1f[4*i+3]=b.w;
        }
    }
    const float zs0 = zsum_np(z0f), zs1 = zsum_np(z1f);
    float bd0 = 3.402823466e38f, bd1 = 3.402823466e38f;
    int bi0 = 0, bi1 = 0;
    for (int t = 0; t < 64; ++t) {
        __syncthreads();
        {
            const float4* src = (const float4*)(emb + (size_t)t * 128 * 64);
            float4* dst = (float4*)tile;
#pragma unroll
            for (int i = 0; i < 8; ++i) dst[tid + i * 256] = src[tid + i * 256];
        }
        __syncthreads();
        const int base = wave * 32;
#pragma unroll 2
        for (int jg = 0; jg < 32; jg += 4) {
            const float* e = tile + (size_t)(base + jg) * 64;
            float a00=0,a10=0,a20=0,a30=0,a01=0,a11=0,a21=0,a31=0;
#pragma unroll
            for (int i = 0; i < 16; ++i) {
                float4 ea = ((const float4*)(e))[i];
                float4 eb = ((const float4*)(e + 64))[i];
                float4 ec = ((const float4*)(e + 128))[i];
                float4 ed = ((const float4*)(e + 192))[i];
                float x0=z0f[4*i],x1=z0f[4*i+1],x2=z0f[4*i+2],x3=z0f[4*i+3];
                float y0=z1f[4*i],y1=z1f[4*i+1],y2=z1f[4*i+2],y3=z1f[4*i+3];
                a00=fmaf(x0,ea.x,a00);a00=fmaf(x1,ea.y,a00);a00=fmaf(x2,ea.z,a00);a00=fmaf(x3,ea.w,a00);
                a10=fmaf(x0,eb.x,a10);a10=fmaf(x1,eb.y,a10);a10=fmaf(x2,eb.z,a10);a10=fmaf(x3,eb.w,a10);
                a20=fmaf(x0,ec.x,a20);a20=fmaf(x1,ec.y,a20);a20=fmaf(x2,ec.z,a20);a20=fmaf(x3,ec.w,a20);
                a30=fmaf(x0,ed.x,a30);a30=fmaf(x1,ed.y,a30);a30=fmaf(x2,ed.z,a30);a30=fmaf(x3,ed.w,a30);
                a01=fmaf(y0,ea.x,a01);a01=fmaf(y1,ea.y,a01);a01=fmaf(y2,ea.z,a01);a01=fmaf(y3,ea.w,a01);
                a11=fmaf(y0,eb.x,a11);a11=fmaf(y1,eb.y,a11);a11=fmaf(y2,eb.z,a11);a11=fmaf(y3,eb.w,a11);
                a21=fmaf(y0,ec.x,a21);a21=fmaf(y1,ec.y,a21);a21=fmaf(y2,ec.z,a21);a21=fmaf(y3,ec.w,a21);
                a31=fmaf(y0,ed.x,a31);a31=fmaf(y1,ed.y,a31);a31=fmaf(y2,ed.z,a31);a31=fmaf(y3,ed.w,a31);
            }
            const int gj = t * 128 + base + jg;
            float d;
            d=fmaf(-2.f,a00,zs0); if(d<bd0){bd0=d;bi0=gj;}
            d=fmaf(-2.f,a10,zs0); if(d<bd0){bd0=d;bi0=gj+1;}
            d=fmaf(-2.f,a20,zs0); if(d<bd0){bd0=d;bi0=gj+2;}
            d=fmaf(-2.f,a30,zs0); if(d<bd0){bd0=d;bi0=gj+3;}
            d=fmaf(-2.f,a01,zs1); if(d<bd1){bd1=d;bi1=gj;}
            d=fmaf(-2.f,a11,zs1); if(d<bd1){bd1=d;bi1=gj+1;}
            d=fmaf(-2.f,a21,zs1); if(d<bd1){bd1=d;bi1=gj+2;}
            d=fmaf(-2.f,a31,zs1); if(d<bd1){bd1=d;bi1=gj+3;}
        }
    }
    red_d[wave][lane]=bd0; red_i[wave][lane]=bi0;
    red_d[wave][lane+64]=bd1; red_i[wave][lane+64]=bi1;
    __syncthreads();
    if (wave == 0) {
        float blk = 0.f;
#pragma unroll
        for (int half = 0; half < 2; ++half) {
            const int lrow = lane + half * 64;
            const float* zrf = half ? z1f : z0f;
            float bd = red_d[0][lrow]; int bi = red_i[0][lrow];
#pragma unroll
            for (int w = 1; w < 4; ++w) {
                float dd = red_d[w][lrow]; int ii = red_i[w][lrow];
                if (dd < bd || (dd == bd && ii < bi)) { bd = dd; bi = ii; }
            }
            const size_t row = (size_t)blockIdx.x * 128 + lrow;
            out[IDX_OFF + row] = (float)bi;
            const float4* ep = (const float4*)(emb + (size_t)bi * 64);
            float4* oq = (float4*)(out + row * 64);
            float ls = 0.f;
#pragma unroll
            for (int i = 0; i < 16; ++i) {
                float4 ev = ep[i];
                oq[i] = ev;
                float dx=ev.x-zrf[4*i], dy=ev.y-zrf[4*i+1];
                float dzv=ev.z-zrf[4*i+2], dw=ev.w-zrf[4*i+3];
                ls=fmaf(dx,dx,ls); ls=fmaf(dy,dy,ls); ls=fmaf(dzv,dzv,ls); ls=fmaf(dw,dw,ls);
            }
            blk += ls;
        }
#pragma unroll
        for (int off = 32; off; off >>= 1) blk += __shfl_down(blk, off);
        if (lane == 0) ws[blockIdx.x] = blk;
    }
}

extern "C" __global__ __launch_bounds__(512)
void vq_legacy_loss(const float* __restrict__ ws, float* __restrict__ out) {
    __shared__ float s[8];
    const int tid = threadIdx.x;
    float v = ws[tid];
#pragma unroll
    for (int off = 32; off; off >>= 1) v += __shfl_down(v, off);
    if ((tid & 63) == 0) s[tid >> 6] = v;
    __syncthreads();
    if (tid == 0) {
        float t = 0.f;
#pragma unroll
        for (int i = 0; i < 8; ++i) t += s[i];
        out[LOSS_OFF] = 1.25f * t / 4194304.f;
    }
}

extern "C" void kernel_launch(void* const* d_in, const int* in_sizes, int n_in,
                              void* d_out, int out_size, void* d_ws, size_t ws_size,
                              hipStream_t stream) {
    const float* z   = (const float*)d_in[0];
    const float* emb = (const float*)d_in[1];
    float* out = (float*)d_out;
    if (ws_size < (size_t)WS_NEED) {              // fallback: proven fp32 path
        float* ws = (float*)d_ws;
        vq_legacy<<<512, 256, 0, stream>>>(z, emb, out, ws);
        vq_legacy_loss<<<1, 512, 0, stream>>>(ws, out);
        return;
    }
    char* wsb = (char*)d_ws;
    u32* efrag = (u32*)(wsb + WS_EFRAG_OFF);
    float* lpart = (float*)(wsb + WS_LPART_OFF);
    u32* queue   = (u32*)(wsb + WS_QUEUE_OFF);
    u32* qcount  = (u32*)(wsb + WS_QCNT_OFF);
    float* loss_over = (float*)(wsb + WS_LOVR_OFF);
    vq_prep<<<256, 256, 0, stream>>>(emb, efrag, qcount, loss_over);
    vq_screen<<<512, 256, 0, stream>>>(z, efrag, emb, out, lpart, queue, qcount);
    vq_over<<<256, 256, 0, stream>>>(z, emb, queue, qcount, out, loss_over);
    vq_lossred<<<1, 256, 0, stream>>>(lpart, loss_over, out);
}

// Round 9
// 203.656 us; speedup vs baseline: 1.7714x; 1.7714x over previous
//
#include <hip/hip_runtime.h>

typedef __attribute__((ext_vector_type(8))) short short8;
typedef __attribute__((ext_vector_type(16))) float floatx16;
typedef unsigned int u32;
typedef unsigned short u16;
typedef unsigned long long u64;

#define NROWS 65536
#define NEMB 8192
#define DIM 64
#define LOSS_OFF ((size_t)NROWS * DIM)   // 4194304
#define IDX_OFF (LOSS_OFF + 1)
#define CAPQ 16                           // slots per (row, sublist)
#define CSTRIDE 66                        // u16 slots per row (64 + 2 pad)
#define NPRE 2                            // prepass tiles (seed runm)

// ws layout (bytes)
#define WS_EFRAG_OFF 0u                   // 1 MB   bf16 fragment-major embedding
#define WS_LPART_OFF (1u << 20)           // 2 KB   per-block loss partials (512)
#define WS_QUEUE_OFF ((1u << 20) + 8192u) // 256 KB overflow queue (65536 slots)
#define WS_QCNT_OFF  ((1u << 20) + 8192u + (256u << 10))
#define WS_LOVR_OFF  (WS_QCNT_OFF + 4u)
#define WS_NEED      (WS_QCNT_OFF + 64u)

typedef const __attribute__((address_space(1))) unsigned int GU32;
typedef __attribute__((address_space(3))) unsigned int LU32;

__device__ __forceinline__ unsigned short f2bf(float f) {  // RNE float->bf16
    u32 x = __float_as_uint(f);
    return (unsigned short)((x + 0x7fffu + ((x >> 16) & 1u)) >> 16);
}

// numpy pairwise-sum replication for sum(z^2) over 64 elements (validated R1)
__device__ __forceinline__ float zsum_np(const float* zf) {
    float r[8];
#pragma unroll
    for (int j = 0; j < 8; ++j) r[j] = zf[j] * zf[j];
#pragma unroll
    for (int i = 8; i < 64; i += 8) {
#pragma unroll
        for (int j = 0; j < 8; ++j) r[j] += zf[i + j] * zf[i + j];
    }
    return ((r[0] + r[1]) + (r[2] + r[3])) + ((r[4] + r[5]) + (r[6] + r[7]));
}

// exact fp32 dot, sequential k-ascending FMA chain (validated R1)
__device__ __forceinline__ float dot_chain(const float* zf, const float* e) {
    float acc = 0.f;
#pragma unroll
    for (int i = 0; i < 16; ++i) {
        float4 ev = ((const float4*)e)[i];
        acc = fmaf(zf[4 * i + 0], ev.x, acc);
        acc = fmaf(zf[4 * i + 1], ev.y, acc);
        acc = fmaf(zf[4 * i + 2], ev.z, acc);
        acc = fmaf(zf[4 * i + 3], ev.w, acc);
    }
    return acc;
}

// max of 16 via v_max3_f32-friendly triples
__device__ __forceinline__ float vmax16_3(const floatx16& a) {
    float m0 = fmaxf(fmaxf(a[0], a[1]), a[2]);
    float m1 = fmaxf(fmaxf(a[3], a[4]), a[5]);
    float m2 = fmaxf(fmaxf(a[6], a[7]), a[8]);
    float m3 = fmaxf(fmaxf(a[9], a[10]), a[11]);
    float m4 = fmaxf(fmaxf(a[12], a[13]), a[14]);
    float n0 = fmaxf(fmaxf(m0, m1), m2);
    float n1 = fmaxf(fmaxf(m3, m4), a[15]);
    return fmaxf(n0, n1);
}

// ---------- pass 0: convert embeddings to fragment-major bf16 ----------
extern "C" __global__ __launch_bounds__(256)
void vq_prep(const float* __restrict__ emb, u32* __restrict__ efrag,
             u32* __restrict__ qcount, float* __restrict__ loss_over) {
    int tid = blockIdx.x * 256 + threadIdx.x;     // 65536 threads
    int t = tid >> 8, kc = (tid >> 5) & 7, m = tid & 31;
    const float* e = emb + (((size_t)t * 32 + m) * 64 + kc * 8);
    float4 a = ((const float4*)e)[0];
    float4 b = ((const float4*)e)[1];
    u32 w0 = (u32)f2bf(a.x) | ((u32)f2bf(a.y) << 16);
    u32 w1 = (u32)f2bf(a.z) | ((u32)f2bf(a.w) << 16);
    u32 w2 = (u32)f2bf(b.x) | ((u32)f2bf(b.y) << 16);
    u32 w3 = (u32)f2bf(b.z) | ((u32)f2bf(b.w) << 16);
    ((uint4*)efrag)[tid] = make_uint4(w0, w1, w2, w3);
    if (tid == 0) { qcount[0] = 0u; *loss_over = 0.f; }
}

// ---------- fused screen + exact rescore + outputs ----------
// 512 blocks x 256 thr, 128 rows/block, LDS ~53 KB -> 3 blocks/CU at VGPR~108.
// Phase A: bf16 MFMA screen with cross-lane runm sharing (the 4 sublanes of a
//          row merge their running max each iter: h-pair via shfl_xor32 (free),
//          wave-pair via LDS (stale-read safe: runm monotone, any stale value
//          <= true max keeps thr conservative)). Candidates -> LDS u16 lists.
// Phase C: exact fp32 rescore, 2 lanes/row (validated R5 numerics).
// Phase D: z_q + loss epilogue. Overflow rows -> queue -> vq_over.
extern "C" __global__ __launch_bounds__(256, 2)
void vq_screen(const float* __restrict__ z, const u32* __restrict__ efrag,
               const float* __restrict__ emb, float* __restrict__ out,
               float* __restrict__ lpart, u32* __restrict__ queue,
               u32* __restrict__ qcount) {
    __shared__ u32 etile[8192];                   // 32 KB e-stage
    __shared__ u16 cand[128 * CSTRIDE];           // 16.5 KB candidate sublists
    __shared__ u32 cnt_l[512];                    // 2 KB: 128 rows x 4 subs
    __shared__ float runm_sh[128][2];             // 1 KB cross-wave runm share
    __shared__ u32 win[128];
    __shared__ float lsum[4];
    const int tid = threadIdx.x;
    const int wave = tid >> 6, lane = tid & 63;
    const int rlo = lane & 31, h = lane >> 5;
    const int rowbase = blockIdx.x * 128 + (wave >> 1) * 64;
    const int sub = (wave & 1) * 2 + h;           // sublist id 0..3
    const int wp = wave & 1;                      // wave-pair id

    if (tid < 128) { runm_sh[tid][0] = -3.4e38f; runm_sh[tid][1] = -3.4e38f; }

    // --- z fragments (persistent, B-operand: n=lane&31, k=(lane>>5)*8+j) ---
    short8 zfr[2][4];
    float eps_[2];
#pragma unroll
    for (int rt = 0; rt < 2; ++rt) {
        const float* zp = z + (size_t)(rowbase + rt * 32 + rlo) * 64;
        float sa = 0.f;
#pragma unroll
        for (int s = 0; s < 4; ++s) {
            const float4* p = (const float4*)(zp + s * 16 + h * 8);
            float4 a = p[0], b = p[1];
            union { short8 v; unsigned short e[8]; } u;
            u.e[0] = f2bf(a.x); u.e[1] = f2bf(a.y);
            u.e[2] = f2bf(a.z); u.e[3] = f2bf(a.w);
            u.e[4] = f2bf(b.x); u.e[5] = f2bf(b.y);
            u.e[6] = f2bf(b.z); u.e[7] = f2bf(b.w);
            zfr[rt][s] = u.v;
            sa += fabsf(a.x) + fabsf(a.y) + fabsf(a.z) + fabsf(a.w)
                + fabsf(b.x) + fabsf(b.y) + fabsf(b.z) + fabsf(b.w);
        }
        sa += __shfl_xor(sa, 32);                 // combine the two k-halves
        eps_[rt] = fmaf(1.1e-6f, sa, 1e-7f);      // validated R2 margin
    }
    float runm[2] = { -3.4e38f, -3.4e38f };
    u32 pc[2] = { 0u, 0u };                       // lane-private append counts

    // ===== Phase A: ii<NPRE prepass (seed runm); then full 32-tile scan
    for (int ii = 0; ii < 32 + NPRE; ++ii) {
        const int t = (ii < NPRE) ? ii : (ii - NPRE);
        __syncthreads();
        {
            const u32* g = efrag + (size_t)t * 8192 + tid * 4;
            u32* l = etile + tid * 4;
#pragma unroll
            for (int r = 0; r < 8; ++r)
                __builtin_amdgcn_global_load_lds((GU32*)(g + r * 1024),
                                                 (LU32*)(l + r * 1024), 16, 0, 0);
        }
        __syncthreads();

        // merge partner wave-pair's published runm (stale-ok, monotone)
#pragma unroll
        for (int rt = 0; rt < 2; ++rt) {
            const int rowl = (wave >> 1) * 64 + rt * 32 + rlo;
            runm[rt] = fmaxf(runm[rt], runm_sh[rowl][wp ^ 1]);
        }

        floatx16 acc[4][2];
#pragma unroll
        for (int et = 0; et < 4; ++et)
#pragma unroll
            for (int rt = 0; rt < 2; ++rt) acc[et][rt] = 0.f;

#pragma unroll
        for (int s = 0; s < 4; ++s) {
            short8 af[4];
#pragma unroll
            for (int et = 0; et < 4; ++et) {
                int off = wp * 16384 + et * 4096 + (2 * s + h) * 512 + rlo * 16;
                af[et] = *(const short8*)((const char*)etile + off);
            }
#pragma unroll
            for (int et = 0; et < 4; ++et)
#pragma unroll
                for (int rt = 0; rt < 2; ++rt)
                    acc[et][rt] = __builtin_amdgcn_mfma_f32_32x32x16_bf16(
                        af[et], zfr[rt][s], acc[et][rt], 0, 0, 0);
        }

#pragma unroll
        for (int rt = 0; rt < 2; ++rt) {
            const int rowl = (wave >> 1) * 64 + rt * 32 + rlo;
            float vm[4];
#pragma unroll
            for (int et = 0; et < 4; ++et) vm[et] = vmax16_3(acc[et][rt]);
            float m64 = fmaxf(fmaxf(vm[0], vm[1]), fmaxf(vm[2], vm[3]));
            runm[rt] = fmaxf(runm[rt], m64);
            // h-pair merge (same row, free): thr reflects both halves
            runm[rt] = fmaxf(runm[rt], __shfl_xor(runm[rt], 32));
            if (ii >= NPRE) {
                const float thr = runm[rt] - eps_[rt];
                if (m64 >= thr) {
                    const int ebase = t * 256 + wp * 128;
                    const u32 cbase = (u32)rowl * CSTRIDE + (u32)sub * CAPQ;
#pragma unroll
                    for (int et = 0; et < 4; ++et) {
                        if (vm[et] >= thr) {      // per-et gate: 16-scan only
#pragma unroll
                            for (int r = 0; r < 16; ++r) {
                                float v = acc[et][rt][r];
                                if (v >= thr) {
                                    int j = ebase + et * 32 + ((r & 3) + 8 * (r >> 2) + 4 * h);
                                    if (pc[rt] < CAPQ) cand[cbase + pc[rt]] = (u16)j;
                                    pc[rt]++;     // no atomics
                                }
                            }
                        }
                    }
                }
            }
            // publish merged runm for partner wave-pair (h lanes agree)
            if (h == 0) runm_sh[rowl][wp] = runm[rt];
        }
    }
    // ===== Phase B: publish counts
#pragma unroll
    for (int rt = 0; rt < 2; ++rt)
        cnt_l[(((wave >> 1) * 64 + rt * 32 + rlo) << 2) + sub] = pc[rt];
    __syncthreads();

    // ===== Phase C: exact fp32 rescore, 2 lanes per row
    {
        const int rl = lane & 31, half = lane >> 5;
        const int rowl = wave * 32 + rl;
        const int grow = blockIdx.x * 128 + rowl;
        const u32 ca = cnt_l[(rowl << 2) + 2 * half];
        const u32 cb = cnt_l[(rowl << 2) + 2 * half + 1];
        u32 ovf = (u32)((ca > CAPQ) | (cb > CAPQ));
        ovf |= (u32)__shfl_xor((int)ovf, 32);     // pair-OR (same row)

        if (!ovf) {
            float zf[64];
            const float4* zp = (const float4*)(z + (size_t)grow * 64);
#pragma unroll
            for (int i = 0; i < 16; ++i) {
                float4 a = zp[i];
                zf[4 * i + 0] = a.x; zf[4 * i + 1] = a.y;
                zf[4 * i + 2] = a.z; zf[4 * i + 3] = a.w;
            }
            const float zs = zsum_np(zf);
            u64 best = ~0ull;
            const u32 cbase = (u32)rowl * CSTRIDE + (u32)(2 * half) * CAPQ;
            for (u32 s = 0; s < ca; ++s) {
                u32 j = (u32)cand[cbase + s];
                float d = fmaf(-2.f, dot_chain(zf, emb + (size_t)j * 64), zs);
                u64 p = ((u64)__float_as_uint(d) << 32) | (u64)j;
                best = p < best ? p : best;
            }
            for (u32 s = 0; s < cb; ++s) {
                u32 j = (u32)cand[cbase + CAPQ + s];
                float d = fmaf(-2.f, dot_chain(zf, emb + (size_t)j * 64), zs);
                u64 p = ((u64)__float_as_uint(d) << 32) | (u64)j;
                best = p < best ? p : best;
            }
            u64 o = __shfl_xor(best, 32);         // pair-reduce (same row)
            best = o < best ? o : best;
            if (half == 0) {
                win[rowl] = (u32)best;
                out[IDX_OFF + grow] = (float)(u32)best;
            }
        } else if (half == 0) {
            // queue has 65536 slots = max possible overflow rows: no full case
            u32 pos = atomicAdd(qcount, 1u);
            queue[pos] = (u32)grow;
            win[rowl] = 0xFFFFFFFFu;
        }
    }
    __syncthreads();

    // ===== Phase D: z_q + loss epilogue (2 threads per row)
    float lp = 0.f;
    {
        const int r2 = tid >> 1, hf = tid & 1;
        const int grow2 = blockIdx.x * 128 + r2;
        const u32 wj = win[r2];
        if (wj != 0xFFFFFFFFu) {
            const float4* ep = (const float4*)(emb + (size_t)wj * 64) + hf * 8;
            const float4* zp4 = (const float4*)(z + (size_t)grow2 * 64) + hf * 8;
            float4* oq = (float4*)(out + (size_t)grow2 * 64) + hf * 8;
#pragma unroll
            for (int i = 0; i < 8; ++i) {
                float4 ev = ep[i];
                float4 zv = zp4[i];
                oq[i] = ev;
                float dx = ev.x - zv.x, dy = ev.y - zv.y;
                float dzv = ev.z - zv.z, dw = ev.w - zv.w;
                lp = fmaf(dx, dx, fmaf(dy, dy, fmaf(dzv, dzv, fmaf(dw, dw, lp))));
            }
        }
    }
#pragma unroll
    for (int off = 32; off; off >>= 1) lp += __shfl_down(lp, off);
    if (lane == 0) lsum[wave] = lp;
    __syncthreads();
    if (tid == 0)
        lpart[blockIdx.x] = (lsum[0] + lsum[1]) + (lsum[2] + lsum[3]);
}

// ---------- block-parallel drain of overflow rows ----------
extern "C" __global__ __launch_bounds__(256)
void vq_over(const float* __restrict__ z, const float* __restrict__ emb,
             const u32* __restrict__ queue, const u32* __restrict__ qcount,
             float* __restrict__ out, float* __restrict__ loss_over) {
    __shared__ u64 red[4];
    const int tid = threadIdx.x, wave = tid >> 6, lane = tid & 63;
    u32 n = qcount[0]; if (n > (u32)NROWS) n = (u32)NROWS;
    for (u32 qi = blockIdx.x; qi < n; qi += gridDim.x) {
        const int row = (int)queue[qi];
        const float4* zp = (const float4*)(z + (size_t)row * 64);
        float zf[64];
#pragma unroll
        for (int i = 0; i < 16; ++i) {
            float4 a = zp[i];
            zf[4 * i + 0] = a.x; zf[4 * i + 1] = a.y;
            zf[4 * i + 2] = a.z; zf[4 * i + 3] = a.w;
        }
        const float zs = zsum_np(zf);
        u64 best = ~0ull;
#pragma unroll 2
        for (int j = tid; j < NEMB; j += 256) {
            float d = fmaf(-2.f, dot_chain(zf, emb + (size_t)j * 64), zs);
            u64 p = ((u64)__float_as_uint(d) << 32) | (u64)j;
            best = p < best ? p : best;
        }
#pragma unroll
        for (int off = 32; off; off >>= 1) {
            u64 o = __shfl_xor(best, off);
            best = o < best ? o : best;
        }
        if (lane == 0) red[wave] = best;
        __syncthreads();
        if (tid == 0) {
            u64 b = red[0];
#pragma unroll
            for (int w = 1; w < 4; ++w) { u64 o = red[w]; b = o < b ? o : b; }
            red[0] = b;
            out[IDX_OFF + row] = (float)(u32)b;
        }
        __syncthreads();
        const u32 wj = (u32)red[0];
        float lp = 0.f;
        if (tid < 16) {
            float4 ev = ((const float4*)(emb + (size_t)wj * 64))[tid];
            float4 zv = zp[tid];
            ((float4*)(out + (size_t)row * 64))[tid] = ev;
            float dx = ev.x - zv.x, dy = ev.y - zv.y;
            float dzv = ev.z - zv.z, dw = ev.w - zv.w;
            lp = fmaf(dx, dx, fmaf(dy, dy, fmaf(dzv, dzv, dw * dw)));
        }
        if (wave == 0) {
#pragma unroll
            for (int off = 32; off; off >>= 1) lp += __shfl_down(lp, off);
            if (tid == 0) atomicAdd(loss_over, lp);
        }
        __syncthreads();
    }
}

extern "C" __global__ __launch_bounds__(256)
void vq_lossred(const float* __restrict__ lpart,
                const float* __restrict__ loss_over, float* __restrict__ out) {
    __shared__ float s[256];
    const int tid = threadIdx.x;
    float v = 0.f;
    for (int i = tid; i < 512; i += 256) v += lpart[i];
    s[tid] = v; __syncthreads();
    for (int off = 128; off; off >>= 1) {
        if (tid < off) s[tid] += s[tid + off];
        __syncthreads();
    }
    if (tid == 0) out[LOSS_OFF] = 1.25f * (s[0] + *loss_over) / 4194304.f;
}

// ================= legacy fp32 path (R1, proven) — ws-size fallback ==========
extern "C" __global__ __launch_bounds__(256, 2)
void vq_legacy(const float* __restrict__ z, const float* __restrict__ emb,
               float* __restrict__ out, float* __restrict__ ws) {
    __shared__ float tile[128 * 64];
    __shared__ float red_d[4][128];
    __shared__ int   red_i[4][128];
    const int tid = threadIdx.x, lane = tid & 63, wave = tid >> 6;
    const int r0 = blockIdx.x * 128 + lane;
    float z0f[64], z1f[64];
    {
        const float4* p0 = (const float4*)(z + (size_t)r0 * 64);
        const float4* p1 = (const float4*)(z + ((size_t)r0 + 64) * 64);
#pragma unroll
        for (int i = 0; i < 16; ++i) {
            float4 a = p0[i];
            z0f[4*i+0]=a.x; z0f[4*i+1]=a.y; z0f[4*i+2]=a.z; z0f[4*i+3]=a.w;
            float4 b = p1[i];
            z1f[4*i+0]=b.x; z1f[4*i+1]=b.y; z1f[4*i+2]=b.z; z1f[4*i+3]=b.w;
        }
    }
    const float zs0 = zsum_np(z0f), zs1 = zsum_np(z1f);
    float bd0 = 3.402823466e38f, bd1 = 3.402823466e38f;
    int bi0 = 0, bi1 = 0;
    for (int t = 0; t < 64; ++t) {
        __syncthreads();
        {
            const float4* src = (const float4*)(emb + (size_t)t * 128 * 64);
            float4* dst = (float4*)tile;
#pragma unroll
            for (int i = 0; i < 8; ++i) dst[tid + i * 256] = src[tid + i * 256];
        }
        __syncthreads();
        const int base = wave * 32;
#pragma unroll 2
        for (int jg = 0; jg < 32; jg += 4) {
            const float* e = tile + (size_t)(base + jg) * 64;
            float a00=0,a10=0,a20=0,a30=0,a01=0,a11=0,a21=0,a31=0;
#pragma unroll
            for (int i = 0; i < 16; ++i) {
                float4 ea = ((const float4*)(e))[i];
                float4 eb = ((const float4*)(e + 64))[i];
                float4 ec = ((const float4*)(e + 128))[i];
                float4 ed = ((const float4*)(e + 192))[i];
                float x0=z0f[4*i],x1=z0f[4*i+1],x2=z0f[4*i+2],x3=z0f[4*i+3];
                float y0=z1f[4*i],y1=z1f[4*i+1],y2=z1f[4*i+2],y3=z1f[4*i+3];
                a00=fmaf(x0,ea.x,a00);a00=fmaf(x1,ea.y,a00);a00=fmaf(x2,ea.z,a00);a00=fmaf(x3,ea.w,a00);
                a10=fmaf(x0,eb.x,a10);a10=fmaf(x1,eb.y,a10);a10=fmaf(x2,eb.z,a10);a10=fmaf(x3,eb.w,a10);
                a20=fmaf(x0,ec.x,a20);a20=fmaf(x1,ec.y,a20);a20=fmaf(x2,ec.z,a20);a20=fmaf(x3,ec.w,a20);
                a30=fmaf(x0,ed.x,a30);a30=fmaf(x1,ed.y,a30);a30=fmaf(x2,ed.z,a30);a30=fmaf(x3,ed.w,a30);
                a01=fmaf(y0,ea.x,a01);a01=fmaf(y1,ea.y,a01);a01=fmaf(y2,ea.z,a01);a01=fmaf(y3,ea.w,a01);
                a11=fmaf(y0,eb.x,a11);a11=fmaf(y1,eb.y,a11);a11=fmaf(y2,eb.z,a11);a11=fmaf(y3,eb.w,a11);
                a21=fmaf(y0,ec.x,a21);a21=fmaf(y1,ec.y,a21);a21=fmaf(y2,ec.z,a21);a21=fmaf(y3,ec.w,a21);
                a31=fmaf(y0,ed.x,a31);a31=fmaf(y1,ed.y,a31);a31=fmaf(y2,ed.z,a31);a31=fmaf(y3,ed.w,a31);
            }
            const int gj = t * 128 + base + jg;
            float d;
            d=fmaf(-2.f,a00,zs0); if(d<bd0){bd0=d;bi0=gj;}
            d=fmaf(-2.f,a10,zs0); if(d<bd0){bd0=d;bi0=gj+1;}
            d=fmaf(-2.f,a20,zs0); if(d<bd0){bd0=d;bi0=gj+2;}
            d=fmaf(-2.f,a30,zs0); if(d<bd0){bd0=d;bi0=gj+3;}
            d=fmaf(-2.f,a01,zs1); if(d<bd1){bd1=d;bi1=gj;}
            d=fmaf(-2.f,a11,zs1); if(d<bd1){bd1=d;bi1=gj+1;}
            d=fmaf(-2.f,a21,zs1); if(d<bd1){bd1=d;bi1=gj+2;}
            d=fmaf(-2.f,a31,zs1); if(d<bd1){bd1=d;bi1=gj+3;}
        }
    }
    red_d[wave][lane]=bd0; red_i[wave][lane]=bi0;
    red_d[wave][lane+64]=bd1; red_i[wave][lane+64]=bi1;
    __syncthreads();
    if (wave == 0) {
        float blk = 0.f;
#pragma unroll
        for (int half = 0; half < 2; ++half) {
            const int lrow = lane + half * 64;
            const float* zrf = half ? z1f : z0f;
            float bd = red_d[0][lrow]; int bi = red_i[0][lrow];
#pragma unroll
            for (int w = 1; w < 4; ++w) {
                float dd = red_d[w][lrow]; int ii = red_i[w][lrow];
                if (dd < bd || (dd == bd && ii < bi)) { bd = dd; bi = ii; }
            }
            const size_t row = (size_t)blockIdx.x * 128 + lrow;
            out[IDX_OFF + row] = (float)bi;
            const float4* ep = (const float4*)(emb + (size_t)bi * 64);
            float4* oq = (float4*)(out + row * 64);
            float ls = 0.f;
#pragma unroll
            for (int i = 0; i < 16; ++i) {
                float4 ev = ep[i];
                oq[i] = ev;
                float dx=ev.x-zrf[4*i], dy=ev.y-zrf[4*i+1];
                float dzv=ev.z-zrf[4*i+2], dw=ev.w-zrf[4*i+3];
                ls=fmaf(dx,dx,ls); ls=fmaf(dy,dy,ls); ls=fmaf(dzv,dzv,ls); ls=fmaf(dw,dw,ls);
            }
            blk += ls;
        }
#pragma unroll
        for (int off = 32; off; off >>= 1) blk += __shfl_down(blk, off);
        if (lane == 0) ws[blockIdx.x] = blk;
    }
}

extern "C" __global__ __launch_bounds__(512)
void vq_legacy_loss(const float* __restrict__ ws, float* __restrict__ out) {
    __shared__ float s[8];
    const int tid = threadIdx.x;
    float v = ws[tid];
#pragma unroll
    for (int off = 32; off; off >>= 1) v += __shfl_down(v, off);
    if ((tid & 63) == 0) s[tid >> 6] = v;
    __syncthreads();
    if (tid == 0) {
        float t = 0.f;
#pragma unroll
        for (int i = 0; i < 8; ++i) t += s[i];
        out[LOSS_OFF] = 1.25f * t / 4194304.f;
    }
}

extern "C" void kernel_launch(void* const* d_in, const int* in_sizes, int n_in,
                              void* d_out, int out_size, void* d_ws, size_t ws_size,
                              hipStream_t stream) {
    const float* z   = (const float*)d_in[0];
    const float* emb = (const float*)d_in[1];
    float* out = (float*)d_out;
    if (ws_size < (size_t)WS_NEED) {              // fallback: proven fp32 path
        float* ws = (float*)d_ws;
        vq_legacy<<<512, 256, 0, stream>>>(z, emb, out, ws);
        vq_legacy_loss<<<1, 512, 0, stream>>>(ws, out);
        return;
    }
    char* wsb = (char*)d_ws;
    u32* efrag = (u32*)(wsb + WS_EFRAG_OFF);
    float* lpart = (float*)(wsb + WS_LPART_OFF);
    u32* queue   = (u32*)(wsb + WS_QUEUE_OFF);
    u32* qcount  = (u32*)(wsb + WS_QCNT_OFF);
    float* loss_over = (float*)(wsb + WS_LOVR_OFF);
    vq_prep<<<256, 256, 0, stream>>>(emb, efrag, qcount, loss_over);
    vq_screen<<<512, 256, 0, stream>>>(z, efrag, emb, out, lpart, queue, qcount);
    vq_over<<<256, 256, 0, stream>>>(z, emb, queue, qcount, out, loss_over);
    vq_lossred<<<1, 256, 0, stream>>>(lpart, loss_over, out);
}